// Round 6
// baseline (4553.265 us; speedup 1.0000x reference)
//
#include <hip/hip_runtime.h>
#include <hip/hip_bf16.h>

#define NN 100000
#define NMC 128
#define SS 6
#define EE 100000
#define ELR 30000
#define LLAYERS 4
#define TOT_E (12*EE + 2*ELR)          // 1,260,000
#define SCB 2048                        // elems per scan block
#define NSCB 49                         // ceil(NN/SCB)

typedef short s16x8 __attribute__((ext_vector_type(8)));
typedef float f32x4 __attribute__((ext_vector_type(4)));

__device__ inline unsigned short f2bf(float f) {
  __bf16 h = (__bf16)f;
  return __builtin_bit_cast(unsigned short, h);
}
__device__ inline float bf2f(unsigned short u) {
  unsigned int b = ((unsigned int)u) << 16;
  return __builtin_bit_cast(float, b);
}

// ---------------------------------------------------------------------------
// Weight pool: all 66 [128][128] matrices converted f32 -> bf16 once per call.
// idx: 0 in2, 1 seg2, 2..5 ctr, 6..29 pre, 30..53 suc, 54..57 left,
//      58..61 right, 62..65 ctr2
// ---------------------------------------------------------------------------
__global__ __launch_bounds__(256) void k_wconv(
    const float* __restrict__ in2, const float* __restrict__ seg2,
    const float* __restrict__ ctr, const float* __restrict__ pre,
    const float* __restrict__ suc, const float* __restrict__ lw,
    const float* __restrict__ rw, const float* __restrict__ ctr2,
    __hip_bfloat16* __restrict__ Wb)
{
  const int total = 66 * NMC * NMC;
  for (int i = blockIdx.x * blockDim.x + threadIdx.x; i < total;
       i += gridDim.x * blockDim.x) {
    const int m = i >> 14, within = i & 16383;
    const float* src; int rel;
    if      (m == 0) { src = in2;  rel = 0; }
    else if (m == 1) { src = seg2; rel = 0; }
    else if (m < 6)  { src = ctr;  rel = m - 2; }
    else if (m < 30) { src = pre;  rel = m - 6; }
    else if (m < 54) { src = suc;  rel = m - 30; }
    else if (m < 58) { src = lw;   rel = m - 54; }
    else if (m < 62) { src = rw;   rel = m - 58; }
    else             { src = ctr2; rel = m - 62; }
    Wb[i] = __hip_bfloat16(bf2f(f2bf(src[rel * 16384 + within])));
  }
}

// ---------------------------------------------------------------------------
// CSR build. After k_scatter, ofs[s][u] = END offset of node u's edge list
// (set-local); start = (u==0) ? 0 : ofs[s][u-1]. vS entries pack
// v (bits 0..16) | u_local = u&31 (bits 17..21): any reader of an entry is
// the block owning rows [u&~31, u|31], so only u&31 is needed.
// ---------------------------------------------------------------------------
__device__ inline void edge_decode(int idx, int& s, int& e) {
  if (idx < 12 * EE) { s = idx / EE; e = idx - s * EE; }
  else { int r = idx - 12 * EE; s = 12 + r / ELR; e = r - (s - 12) * ELR; }
}
__device__ inline int edge_u(int s, int e,
    const int* pu, const int* su, const int* lu, const int* ru) {
  if (s < 6)  return pu[s * EE + e];
  if (s < 12) return su[(s - 6) * EE + e];
  if (s == 12) return lu[e];
  return ru[e];
}
__device__ inline int edge_v(int s, int e,
    const int* pv, const int* sv, const int* lv, const int* rv) {
  if (s < 6)  return pv[s * EE + e];
  if (s < 12) return sv[(s - 6) * EE + e];
  if (s == 12) return lv[e];
  return rv[e];
}
__device__ inline int set_base(int s) {
  return (s < 12) ? s * EE : 12 * EE + (s - 12) * ELR;
}

__global__ __launch_bounds__(256) void k_hist(
    const int* __restrict__ pu, const int* __restrict__ su,
    const int* __restrict__ lu, const int* __restrict__ ru,
    int* __restrict__ cnt)
{
  for (int i = blockIdx.x * blockDim.x + threadIdx.x; i < TOT_E;
       i += gridDim.x * blockDim.x) {
    int s, e; edge_decode(i, s, e);
    atomicAdd(&cnt[s * NN + edge_u(s, e, pu, su, lu, ru)], 1);
  }
}

__global__ __launch_bounds__(256) void k_scan1(
    const int* __restrict__ cnt, int* __restrict__ ofs, int* __restrict__ btot)
{
  const int s = blockIdx.x / NSCB, b = blockIdx.x % NSCB;
  const int base = s * NN + b * SCB;
  const int lim = min(SCB, NN - b * SCB);
  const int t = threadIdx.x;
  int loc[8]; int sum = 0;
  #pragma unroll
  for (int j = 0; j < 8; ++j) {
    const int idx = t * 8 + j;
    const int v = (idx < lim) ? cnt[base + idx] : 0;
    loc[j] = sum; sum += v;
  }
  __shared__ int sh[256];
  sh[t] = sum;
  __syncthreads();
  for (int off = 1; off < 256; off <<= 1) {
    const int v = (t >= off) ? sh[t - off] : 0;
    __syncthreads();
    sh[t] += v;
    __syncthreads();
  }
  const int excl = (t == 0) ? 0 : sh[t - 1];
  #pragma unroll
  for (int j = 0; j < 8; ++j) {
    const int idx = t * 8 + j;
    if (idx < lim) ofs[base + idx] = loc[j] + excl;
  }
  if (t == 255) btot[s * 64 + b] = sh[255];
}

__global__ __launch_bounds__(64) void k_scan2(int* __restrict__ btot)
{
  if (threadIdx.x != 0) return;
  const int s = blockIdx.x;
  int run = 0;
  for (int b = 0; b < NSCB; ++b) {
    const int tmp = btot[s * 64 + b];
    btot[s * 64 + b] = run;
    run += tmp;
  }
}

__global__ __launch_bounds__(256) void k_scan3(
    int* __restrict__ ofs, const int* __restrict__ btot)
{
  const int total = 14 * NN;
  for (int i = blockIdx.x * blockDim.x + threadIdx.x; i < total;
       i += gridDim.x * blockDim.x) {
    const int s = i / NN, u = i - s * NN;
    ofs[i] += btot[s * 64 + u / SCB];
  }
}

__global__ __launch_bounds__(256) void k_scatter(
    const int* __restrict__ pu, const int* __restrict__ su,
    const int* __restrict__ lu, const int* __restrict__ ru,
    const int* __restrict__ pv, const int* __restrict__ sv,
    const int* __restrict__ lv, const int* __restrict__ rv,
    int* __restrict__ ofs, int* __restrict__ vS)
{
  for (int i = blockIdx.x * blockDim.x + threadIdx.x; i < TOT_E;
       i += gridDim.x * blockDim.x) {
    int s, e; edge_decode(i, s, e);
    const int u = edge_u(s, e, pu, su, lu, ru);
    const int v = edge_v(s, e, pv, sv, lv, rv);
    const int pos = atomicAdd(&ofs[s * NN + u], 1);
    vS[set_base(s) + pos] = v | ((u & 31) << 17);
  }
}

// ---------------------------------------------------------------------------
// k_stem1b: outb[n][o] = relu(w1[o][:2] . x[n][:2] + b1[o]), bf16 out.
// ---------------------------------------------------------------------------
__global__ __launch_bounds__(256) void k_stem1b(
    const float* __restrict__ x2, const float* __restrict__ w1,
    const float* __restrict__ b1, __hip_bfloat16* __restrict__ outb)
{
  int64_t i = (int64_t)blockIdx.x * blockDim.x + threadIdx.x;
  const int64_t total = (int64_t)NN * 64;
  const int64_t stride = (int64_t)gridDim.x * blockDim.x;
  for (; i < total; i += stride) {
    const int n = (int)(i >> 6);
    const int o = (int)(i & 63) * 2;
    const float2 xv = ((const float2*)x2)[n];
    const float v0 = fmaxf(w1[2*o]   * xv.x + w1[2*o+1] * xv.y + b1[o],   0.f);
    const float v1 = fmaxf(w1[2*o+2] * xv.x + w1[2*o+3] * xv.y + b1[o+1], 0.f);
    const unsigned int packed = ((unsigned int)f2bf(v1) << 16) | f2bf(v0);
    *(unsigned int*)&outb[(size_t)n * NMC + o] = packed;
  }
}

// ---------------------------------------------------------------------------
// k_dense<EPI>: Out = Xb @ Wb.T (bf16 A and B, f32 accum), N=100000 rows.
//   EPI=1: GN -> packed bf16 to outb (in-place on Xb is safe)
//   EPI=3: y = relu(GN(acc) + resb) -> outb; if wout, also f32 to outf
// ---------------------------------------------------------------------------
template<int EPI>
__global__ __launch_bounds__(256) void k_dense(
    const __hip_bfloat16* __restrict__ Xb, const __hip_bfloat16* __restrict__ Wbs,
    __hip_bfloat16* __restrict__ outb, float* __restrict__ outf,
    const float* __restrict__ gw, const float* __restrict__ gb,
    const __hip_bfloat16* __restrict__ resb, int wout)
{
  __shared__ float cl[32 * 129];
  const int lane = threadIdx.x & 63;
  const int w = threadIdx.x >> 6;
  const int m = w & 1, ng = w >> 1;
  const int lr = lane & 15, lg = lane >> 4;

  s16x8 B[4][4];
  #pragma unroll
  for (int t4 = 0; t4 < 4; ++t4)
    #pragma unroll
    for (int ks = 0; ks < 4; ++ks)
      B[t4][ks] = *(const s16x8*)&Wbs[(64*ng + 16*t4 + lr) * NMC + 32*ks + 8*lg];

  const float gwc0 = gw[2*lane], gwc1 = gw[2*lane+1];
  const float gbc0 = gb[2*lane], gbc1 = gb[2*lane+1];

  const int nTiles = NN / 32;
  for (int tile = blockIdx.x; tile < nTiles; tile += gridDim.x) {
    const int row = tile*32 + 16*m + lr;
    s16x8 A[4];
    #pragma unroll
    for (int ks = 0; ks < 4; ++ks)
      A[ks] = *(const s16x8*)&Xb[(size_t)row * NMC + 32*ks + 8*lg];

    f32x4 acc[4] = {};
    #pragma unroll
    for (int ks = 0; ks < 4; ++ks)
      #pragma unroll
      for (int t4 = 0; t4 < 4; ++t4)
        acc[t4] = __builtin_amdgcn_mfma_f32_16x16x32_bf16(A[ks], B[t4][ks], acc[t4], 0, 0, 0);

    #pragma unroll
    for (int j = 0; j < 4; ++j) {
      const int r = 16*m + 4*lg + j;
      #pragma unroll
      for (int t4 = 0; t4 < 4; ++t4)
        cl[r * 129 + 64*ng + 16*t4 + lr] = acc[t4][j];
    }
    __syncthreads();
    #pragma unroll
    for (int rr = 0; rr < 8; ++rr) {
      const int r = rr*4 + w;
      const float x0 = cl[r*129 + 2*lane];
      const float x1 = cl[r*129 + 2*lane + 1];
      float s  = x0 + x1;
      float s2 = x0*x0 + x1*x1;
      #pragma unroll
      for (int off = 32; off >= 1; off >>= 1) {
        s  += __shfl_xor(s, off);
        s2 += __shfl_xor(s2, off);
      }
      const float mu = s * (1.f/128.f);
      const float rs = rsqrtf(s2*(1.f/128.f) - mu*mu + 1e-5f);
      float y0 = (x0 - mu)*rs*gwc0 + gbc0;
      float y1 = (x1 - mu)*rs*gwc1 + gbc1;
      const size_t base = (size_t)(tile*32 + r) * NMC + 2*lane;
      if (EPI == 3) {
        const unsigned int rp = *(const unsigned int*)&resb[base];
        y0 = fmaxf(y0 + bf2f((unsigned short)(rp & 0xffff)), 0.f);
        y1 = fmaxf(y1 + bf2f((unsigned short)(rp >> 16)), 0.f);
      }
      const unsigned int packed = ((unsigned int)f2bf(y1) << 16) | f2bf(y0);
      *(unsigned int*)&outb[base] = packed;
      if (EPI == 3 && wout) *(float2*)&outf[base] = make_float2(y0, y1);
    }
    __syncthreads();
  }
}

// ---------------------------------------------------------------------------
// k_spmm: one layer's message passing, EDGE-PARALLEL with LDS scatter.
// Block = 32 output rows, 4 waves. Work slots: 14 CSR sets + 2 identity
// halves; wave w handles slots w, w+4, w+8, w+12. Per set, the block's edges
// are a contiguous CSR range; processed in 16-edge MFMA passes:
//   - 64 lanes gather 16 edge feat-rows in parallel (no serial chains)
//   - MFMA vs W_set (B streamed from L2-hot pool)
//   - C fragments scattered into f32 LDS accumulator via ds_add_f32
//     (u_local comes packed in the vS entry's high bits)
// No global atomics, no per-set barriers. Epilogue: fused GN+ReLU -> tempb.
// ---------------------------------------------------------------------------
__global__ __launch_bounds__(256, 4) void k_spmm(
    const __hip_bfloat16* __restrict__ featb, __hip_bfloat16* __restrict__ tempb,
    const __hip_bfloat16* __restrict__ Wb, const int* __restrict__ ofs,
    const int* __restrict__ vS, const float* __restrict__ gw,
    const float* __restrict__ gb, int layer)
{
  __shared__ float accsm[32 * 128];
  const int t = threadIdx.x;
  const int lane = t & 63, w = t >> 6;
  const int lr = lane & 15, lg = lane >> 4;
  const int r0 = blockIdx.x * 32;

  #pragma unroll
  for (int q = 0; q < 16; ++q) accsm[q * 256 + t] = 0.f;
  __syncthreads();

  for (int slot = w; slot < 16; slot += 4) {
    if (slot < 14) {
      const int s = slot;
      const int st = (r0 == 0) ? 0 : ofs[s * NN + r0 - 1];
      const int en = ofs[s * NN + r0 + 31];
      const int sbase = set_base(s);
      int wbidx;
      if      (s < 6)  wbidx = 6 + layer*6 + s;
      else if (s < 12) wbidx = 30 + layer*6 + (s - 6);
      else if (s == 12) wbidx = 54 + layer;
      else              wbidx = 58 + layer;
      const __hip_bfloat16* Wbs = Wb + (size_t)wbidx * NMC * NMC;

      for (int c0 = st; c0 < en; c0 += 16) {
        const int e = c0 + lr;
        const int packed = (e < en) ? vS[sbase + e] : 0;
        const int v  = packed & 0x1FFFF;
        const int ul = packed >> 17;
        s16x8 A[4];
        #pragma unroll
        for (int ks = 0; ks < 4; ++ks)
          A[ks] = *(const s16x8*)&featb[(size_t)v * NMC + 32*ks + 8*lg];
        // zero-out A for invalid edges (load was safe, data must not count)
        if (e >= en) {
          #pragma unroll
          for (int ks = 0; ks < 4; ++ks) A[ks] = (s16x8)(short)0;
        }
        f32x4 acc[8] = {};
        #pragma unroll
        for (int ks = 0; ks < 4; ++ks)
          #pragma unroll
          for (int t4 = 0; t4 < 8; ++t4) {
            const s16x8 Bf = *(const s16x8*)&Wbs[(16*t4 + lr) * NMC + 32*ks + 8*lg];
            acc[t4] = __builtin_amdgcn_mfma_f32_16x16x32_bf16(A[ks], Bf, acc[t4], 0, 0, 0);
          }
        #pragma unroll
        for (int j = 0; j < 4; ++j) {
          const int rsrc = 4*lg + j;                 // C row = edge index
          const int uj = __shfl(ul, rsrc);           // u_local from A-phase lane
          if (c0 + rsrc < en) {
            #pragma unroll
            for (int t4 = 0; t4 < 8; ++t4)
              atomicAdd(&accsm[uj * 128 + 16*t4 + lr], acc[t4][j]);
          }
        }
      }
    } else {
      // identity (ctr) half: 16 rows r0 + 16*h ..
      const int h = slot - 14;
      const int row = r0 + 16*h + lr;
      const __hip_bfloat16* Wbs = Wb + (size_t)(2 + layer) * NMC * NMC;
      s16x8 A[4];
      #pragma unroll
      for (int ks = 0; ks < 4; ++ks)
        A[ks] = *(const s16x8*)&featb[(size_t)row * NMC + 32*ks + 8*lg];
      f32x4 acc[8] = {};
      #pragma unroll
      for (int ks = 0; ks < 4; ++ks)
        #pragma unroll
        for (int t4 = 0; t4 < 8; ++t4) {
          const s16x8 Bf = *(const s16x8*)&Wbs[(16*t4 + lr) * NMC + 32*ks + 8*lg];
          acc[t4] = __builtin_amdgcn_mfma_f32_16x16x32_bf16(A[ks], Bf, acc[t4], 0, 0, 0);
        }
      #pragma unroll
      for (int j = 0; j < 4; ++j) {
        const int uj = 16*h + 4*lg + j;
        #pragma unroll
        for (int t4 = 0; t4 < 8; ++t4)
          atomicAdd(&accsm[uj * 128 + 16*t4 + lr], acc[t4][j]);
      }
    }
  }
  __syncthreads();

  // ---- fused GroupNorm + ReLU -> tempb ----
  const float gwc0 = gw[2*lane], gwc1 = gw[2*lane+1];
  const float gbc0 = gb[2*lane], gbc1 = gb[2*lane+1];
  #pragma unroll
  for (int rr = 0; rr < 8; ++rr) {
    const int r = rr*4 + w;
    const float x0 = accsm[r*128 + 2*lane];
    const float x1 = accsm[r*128 + 2*lane + 1];
    float s  = x0 + x1;
    float s2 = x0*x0 + x1*x1;
    #pragma unroll
    for (int off = 32; off >= 1; off >>= 1) {
      s  += __shfl_xor(s, off);
      s2 += __shfl_xor(s2, off);
    }
    const float mu = s * (1.f/128.f);
    const float rs = rsqrtf(s2*(1.f/128.f) - mu*mu + 1e-5f);
    const float y0 = fmaxf((x0 - mu)*rs*gwc0 + gbc0, 0.f);
    const float y1 = fmaxf((x1 - mu)*rs*gwc1 + gbc1, 0.f);
    const unsigned int packed = ((unsigned int)f2bf(y1) << 16) | f2bf(y0);
    *(unsigned int*)&tempb[(size_t)(r0 + r) * NMC + 2*lane] = packed;
  }
}

// ---------------------------------------------------------------------------
// k_combine: featb = bf16(relu(fi + fs));  fi in tempb, fs in featb.
// ---------------------------------------------------------------------------
__global__ __launch_bounds__(256) void k_combine(
    const __hip_bfloat16* __restrict__ fib, __hip_bfloat16* __restrict__ featb)
{
  int64_t i = (int64_t)blockIdx.x * blockDim.x + threadIdx.x;
  const int64_t total = (int64_t)NN * 64;
  const int64_t stride = (int64_t)gridDim.x * blockDim.x;
  for (; i < total; i += stride) {
    const unsigned int ap = ((const unsigned int*)fib)[i];
    const unsigned int bp = ((const unsigned int*)featb)[i];
    const float y0 = fmaxf(bf2f((unsigned short)(ap & 0xffff)) + bf2f((unsigned short)(bp & 0xffff)), 0.f);
    const float y1 = fmaxf(bf2f((unsigned short)(ap >> 16))    + bf2f((unsigned short)(bp >> 16)), 0.f);
    ((unsigned int*)featb)[i] = ((unsigned int)f2bf(y1) << 16) | f2bf(y0);
  }
}

// ---------------------------------------------------------------------------
extern "C" void kernel_launch(void* const* d_in, const int* in_sizes, int n_in,
                              void* d_out, int out_size, void* d_ws, size_t ws_size,
                              hipStream_t stream)
{
  const float* ctrs     = (const float*)d_in[0];
  const float* feats    = (const float*)d_in[1];
  const int*   pre_u    = (const int*)d_in[2];
  const int*   pre_v    = (const int*)d_in[3];
  const int*   suc_u    = (const int*)d_in[4];
  const int*   suc_v    = (const int*)d_in[5];
  const int*   left_u   = (const int*)d_in[6];
  const int*   left_v   = (const int*)d_in[7];
  const int*   right_u  = (const int*)d_in[8];
  const int*   right_v  = (const int*)d_in[9];
  const float* in1_w    = (const float*)d_in[10];
  const float* in1_b    = (const float*)d_in[11];
  const float* in2_w    = (const float*)d_in[12];
  const float* in_gn_w  = (const float*)d_in[13];
  const float* in_gn_b  = (const float*)d_in[14];
  const float* seg1_w   = (const float*)d_in[15];
  const float* seg1_b   = (const float*)d_in[16];
  const float* seg2_w   = (const float*)d_in[17];
  const float* seg_gn_w = (const float*)d_in[18];
  const float* seg_gn_b = (const float*)d_in[19];
  const float* ctr_w    = (const float*)d_in[20];
  const float* pre_w    = (const float*)d_in[21];
  const float* suc_w    = (const float*)d_in[22];
  const float* left_w   = (const float*)d_in[23];
  const float* right_w  = (const float*)d_in[24];
  const float* norm_w   = (const float*)d_in[25];
  const float* norm_b   = (const float*)d_in[26];
  const float* ctr2_w   = (const float*)d_in[27];
  const float* ctr2_gn_w= (const float*)d_in[28];
  const float* ctr2_gn_b= (const float*)d_in[29];

  // workspace layout (as round 4/5; vS now carries packed u_local|v)
  char* ws = (char*)d_ws;
  __hip_bfloat16* tempb = (__hip_bfloat16*)(ws);                 // 25,600,000
  __hip_bfloat16* featb = (__hip_bfloat16*)(ws + 25600000);      // 25,600,000
  __hip_bfloat16* Wb    = (__hip_bfloat16*)(ws + 51200000);      //  2,162,688
  int* cnt  = (int*)(ws + 53362688);                             //  5,600,000
  int* ofs  = (int*)(ws + 58962688);                             //  5,600,000
  int* vS   = (int*)(ws + 64562688);                             //  5,040,000
  int* btot = (int*)(ws + 69602688);                             //      3,584
  float* outf = (float*)d_out;

  // ---- weight pool conversion + CSR build (once per call) ----
  k_wconv<<<2048, 256, 0, stream>>>(in2_w, seg2_w, ctr_w, pre_w, suc_w,
                                    left_w, right_w, ctr2_w, Wb);
  hipMemsetAsync(cnt, 0, (size_t)14 * NN * 4, stream);
  k_hist<<<1232, 256, 0, stream>>>(pre_u, suc_u, left_u, right_u, cnt);
  k_scan1<<<14 * NSCB, 256, 0, stream>>>(cnt, ofs, btot);
  k_scan2<<<14, 64, 0, stream>>>(btot);
  k_scan3<<<2048, 256, 0, stream>>>(ofs, btot);
  k_scatter<<<1232, 256, 0, stream>>>(pre_u, suc_u, left_u, right_u,
                                      pre_v, suc_v, left_v, right_v, ofs, vS);

  // ---- stems ----
  k_stem1b<<<2048, 256, 0, stream>>>(ctrs, in1_w, in1_b, tempb);
  k_dense<1><<<3125, 256, 0, stream>>>(tempb, Wb + 0*16384, tempb, nullptr,
                                       in_gn_w, in_gn_b, nullptr, 0);
  k_stem1b<<<2048, 256, 0, stream>>>(feats, seg1_w, seg1_b, featb);
  k_dense<1><<<3125, 256, 0, stream>>>(featb, Wb + 1*16384, featb, nullptr,
                                       seg_gn_w, seg_gn_b, nullptr, 0);
  k_combine<<<2048, 256, 0, stream>>>(tempb, featb);

  // ---- fusion layers: 2 dispatches each ----
  for (int i = 0; i < LLAYERS; ++i) {
    k_spmm<<<NN/32, 256, 0, stream>>>(featb, tempb, Wb, ofs, vS,
                                      norm_w + i*NMC, norm_b + i*NMC, i);
    k_dense<3><<<3125, 256, 0, stream>>>(tempb, Wb + (size_t)(62+i)*16384,
                                         featb, outf,
                                         ctr2_gn_w + i*NMC, ctr2_gn_b + i*NMC,
                                         featb, (i == LLAYERS-1) ? 1 : 0);
  }
}